// Round 9
// baseline (837.081 us; speedup 1.0000x reference)
//
#include <hip/hip_runtime.h>

#define NEGV (-1000000000.0f)
#define N_ITERS 32
#define NBUCK 512
#define B1 256
#define CAP 12288

// ---------------- util (F==64): 16 lanes/row, ILP=2 rows per thread ----------------
__global__ __launch_bounds__(256) void util_kernel64(
    const float* __restrict__ feats, const float* __restrict__ weight,
    const float* __restrict__ bias, float* __restrict__ u, int E, int half)
{
    int tid = blockIdx.x * blockDim.x + threadIdx.x;
    int g = tid >> 4;
    int l = tid & 15;
    if (g >= half) return;
    float4 wv = *reinterpret_cast<const float4*>(weight + l * 4);
    int e1 = g + half;
    bool has2 = (e1 < E);
    float4 a = *reinterpret_cast<const float4*>(feats + (size_t)g * 64 + l * 4);
    float4 b;
    if (has2) b = *reinterpret_cast<const float4*>(feats + (size_t)e1 * 64 + l * 4);
    float sa = a.x * wv.x + a.y * wv.y + a.z * wv.z + a.w * wv.w;
    float sb = has2 ? (b.x * wv.x + b.y * wv.y + b.z * wv.z + b.w * wv.w) : 0.0f;
    // interleaved 16-lane reductions (two independent chains)
    sa += __shfl_xor(sa, 8, 16);  sb += __shfl_xor(sb, 8, 16);
    sa += __shfl_xor(sa, 4, 16);  sb += __shfl_xor(sb, 4, 16);
    sa += __shfl_xor(sa, 2, 16);  sb += __shfl_xor(sb, 2, 16);
    sa += __shfl_xor(sa, 1, 16);  sb += __shfl_xor(sb, 1, 16);
    if (l == 0) {
        float bb = bias[0];
        u[g] = fminf(fmaxf(sa + bb, -100.0f), -1e-6f);
        if (has2) u[e1] = fminf(fmaxf(sb + bb, -100.0f), -1e-6f);
    }
}

// ---------------- util generic fallback ----------------
__global__ __launch_bounds__(256) void util_kernel(
    const float* __restrict__ feats, const float* __restrict__ weight,
    const float* __restrict__ bias, float* __restrict__ u,
    int E, int F)
{
    int e = blockIdx.x * blockDim.x + threadIdx.x;
    if (e >= E) return;
    const float* row = feats + (size_t)e * (size_t)F;
    float acc = 0.0f;
    for (int f = 0; f < F; f += 4) {
        float4 fv = *reinterpret_cast<const float4*>(row + f);
        acc += fv.x * weight[f + 0];
        acc += fv.y * weight[f + 1];
        acc += fv.z * weight[f + 2];
        acc += fv.w * weight[f + 3];
    }
    acc += bias[0];
    acc = fminf(fmaxf(acc, -100.0f), -1e-6f);
    u[e] = acc;
}

// ---------------- pass 1: per-block coarse-bucket histogram (LDS) ----------------
__global__ __launch_bounds__(256) void bucket_count(
    const int* __restrict__ src, int* __restrict__ hists,
    int E, int W, int chunk)
{
    __shared__ int h[NBUCK];
    for (int i = threadIdx.x; i < NBUCK; i += 256) h[i] = 0;
    __syncthreads();
    const int lo = blockIdx.x * chunk;
    const int hi = min(E, lo + chunk);
    for (int e = lo + threadIdx.x; e < hi; e += 256) {
        unsigned k = (unsigned)src[e] / (unsigned)W;
        atomicAdd(&h[k], 1);
    }
    __syncthreads();
    for (int i = threadIdx.x; i < NBUCK; i += 256)
        hists[blockIdx.x * NBUCK + i] = h[i];
}

// ---------------- pass 2: scan + flags init ----------------
__global__ __launch_bounds__(NBUCK) void bucket_scan(
    int* __restrict__ hists, int* __restrict__ bstarts,
    int* __restrict__ flags, int E)
{
    __shared__ int tot[NBUCK];
    __shared__ int sc[NBUCK];
    const int k = threadIdx.x;
    if (k <= N_ITERS) flags[k] = (k == 0) ? 1 : 0;
    int sum = 0;
    for (int b = 0; b < B1; ++b) sum += hists[b * NBUCK + k];
    tot[k] = sum;
    sc[k] = sum;
    __syncthreads();
    for (int off = 1; off < NBUCK; off <<= 1) {
        int v = sc[k];
        if (k >= off) v += sc[k - off];
        __syncthreads();
        sc[k] = v;
        __syncthreads();
    }
    const int start = sc[k] - tot[k];
    bstarts[k] = start;
    if (k == NBUCK - 1) bstarts[NBUCK] = E;
    int run = start;
    for (int b = 0; b < B1; ++b) {
        int c = hists[b * NBUCK + k];
        hists[b * NBUCK + k] = run;
        run += c;
    }
}

// ---------------- pass 3: scatter into coarse buckets; edg = {packed, exp(u) bits} -----
__global__ __launch_bounds__(256) void bucket_scatter(
    const int* __restrict__ src, const int* __restrict__ dst,
    const float* __restrict__ u, const int* __restrict__ hists,
    int2* __restrict__ edg, int E, int W, int chunk)
{
    __shared__ int cur[NBUCK];
    for (int i = threadIdx.x; i < NBUCK; i += 256)
        cur[i] = hists[blockIdx.x * NBUCK + i];
    __syncthreads();
    const int lo = blockIdx.x * chunk;
    const int hi = min(E, lo + chunk);
    for (int e = lo + threadIdx.x; e < hi; e += 256) {
        int s = src[e];
        unsigned k = (unsigned)s / (unsigned)W;
        int pos = atomicAdd(&cur[k], 1);
        unsigned sl = (unsigned)s - k * (unsigned)W;
        int2 rec;
        rec.x = (int)((sl << 20) | (unsigned)dst[e]);
        rec.y = __float_as_int(expf(u[e]));
        edg[pos] = rec;
    }
}

// ---------------- pass 4: fine sort within bucket + ew0 init ----------------
__global__ __launch_bounds__(256) void fine_sort(
    const int* __restrict__ bstarts, int2* __restrict__ edg,
    int* __restrict__ row_ptr, const int* __restrict__ dest_mask,
    float* __restrict__ ew0, int N, int E, int W)
{
    extern __shared__ int smem[];
    int* pks = smem;
    int* ubs = smem + CAP;
    int* fh  = smem + 2 * CAP;

    const int k  = blockIdx.x;
    const int lo = k * W;
    const int nn = min(N, lo + W) - lo;
    if (k == 0 && threadIdx.x == 0) row_ptr[N] = E;
    if (nn <= 0) return;

    // init ew0 for this block's node range
    for (int i = threadIdx.x; i < nn; i += blockDim.x)
        ew0[lo + i] = dest_mask[lo + i] ? 1.0f : 0.0f;

    const int bs  = bstarts[k];
    const int be  = bstarts[k + 1];
    const int cnt = be - bs;

    int ldcnt = min(cnt, CAP);
    for (int i = threadIdx.x; i < ldcnt; i += blockDim.x) {
        int2 r = edg[bs + i];
        pks[i] = r.x;
        ubs[i] = r.y;
    }
    for (int i = threadIdx.x; i < nn; i += blockDim.x) fh[i] = 0;
    __syncthreads();

    for (int i = threadIdx.x; i < ldcnt; i += blockDim.x)
        atomicAdd(&fh[((unsigned)pks[i]) >> 20], 1);
    __syncthreads();

    if (threadIdx.x == 0) {
        int run = bs;
        for (int i = 0; i < nn; ++i) {
            int c = fh[i];
            fh[i] = run;
            row_ptr[lo + i] = run;
            run += c;
        }
    }
    __syncthreads();

    for (int i = threadIdx.x; i < ldcnt; i += blockDim.x) {
        int w = pks[i];
        int pos = atomicAdd(&fh[((unsigned)w) >> 20], 1);
        int2 r;
        r.x = w & 0xFFFFF;
        r.y = ubs[i];
        edg[pos] = r;
    }
}

// ---------------- one exp-domain iteration: 32 lanes/node, convergence-gated ---------
__global__ __launch_bounds__(256) void iter_exp_conv(
    const int* __restrict__ row_ptr, const int2* __restrict__ edg,
    const int* __restrict__ dest_mask,
    const float* __restrict__ ew, float* __restrict__ ew_new,
    const int* __restrict__ flag_prev, const int* __restrict__ flag_prev2,
    int* __restrict__ flag_cur, int N)
{
    __shared__ int blk_changed;
    int tid = blockIdx.x * blockDim.x + threadIdx.x;

    if (*flag_prev == 0) {
        if (*flag_prev2 == 0) return;          // buffers already identical: no-op
        if (tid < N) ew_new[tid] = ew[tid];    // first converged iter: equalize
        return;
    }

    if (threadIdx.x == 0) blk_changed = 0;
    __syncthreads();

    int n = tid >> 5;
    int l = tid & 31;
    if (n < N) {
        int rs = row_ptr[n];
        int re = row_ptr[n + 1];
        float s = 0.0f;
        for (int j = rs + l; j < re; j += 32) {
            int2 r = edg[j];
            s += __int_as_float(r.y) * ew[r.x];
        }
        s += __shfl_xor(s, 16, 32);
        s += __shfl_xor(s, 8, 32);
        s += __shfl_xor(s, 4, 32);
        s += __shfl_xor(s, 2, 32);
        s += __shfl_xor(s, 1, 32);
        if (l == 0) {
            float nv = dest_mask[n] ? 1.0f : s;
            ew_new[n] = nv;
            if (__float_as_int(nv) != __float_as_int(ew[n])) blk_changed = 1;
        }
    }
    __syncthreads();
    if (threadIdx.x == 0 && blk_changed) atomicOr(flag_cur, 1);
}

// ---------------- final: one more iteration then back to log domain ----------------
__global__ __launch_bounds__(256) void final_exp_conv(
    const int* __restrict__ row_ptr, const int2* __restrict__ edg,
    const int* __restrict__ dest_mask,
    const float* __restrict__ ew, float* __restrict__ value,
    const int* __restrict__ flag_prev, int N)
{
    int tid = blockIdx.x * blockDim.x + threadIdx.x;

    if (*flag_prev == 0) {
        if (tid < N) {
            float s = ew[tid];
            value[tid] = dest_mask[tid] ? 0.0f : (s > 0.0f ? logf(s) : NEGV);
        }
        return;
    }

    int n = tid >> 5;
    int l = tid & 31;
    if (n >= N) return;
    int rs = row_ptr[n];
    int re = row_ptr[n + 1];
    float s = 0.0f;
    for (int j = rs + l; j < re; j += 32) {
        int2 r = edg[j];
        s += __int_as_float(r.y) * ew[r.x];
    }
    s += __shfl_xor(s, 16, 32);
    s += __shfl_xor(s, 8, 32);
    s += __shfl_xor(s, 4, 32);
    s += __shfl_xor(s, 2, 32);
    s += __shfl_xor(s, 1, 32);
    if (l == 0)
        value[n] = dest_mask[n] ? 0.0f : (s > 0.0f ? logf(s) : NEGV);
}

// ---------------- prob = exp((u + v[dst]) - v[src]) ----------------
__global__ __launch_bounds__(256) void prob_kernel(
    const float* __restrict__ u, const int* __restrict__ src,
    const int* __restrict__ dst, const float* __restrict__ v,
    float* __restrict__ prob, int E)
{
    int e = blockIdx.x * blockDim.x + threadIdx.x;
    if (e >= E) return;
    prob[e] = expf((u[e] + v[dst[e]]) - v[src[e]]);
}

// ================= zero-workspace fallback (atomic multi-launch path) ================
__global__ __launch_bounds__(256) void init_pass(
    const int* __restrict__ dest_mask, float* v, float* s, int N)
{
    int n = blockIdx.x * blockDim.x + threadIdx.x;
    if (n >= N) return;
    v[n] = dest_mask[n] ? 0.0f : NEGV;
    s[n] = 0.0f;
}
__global__ __launch_bounds__(256) void edge_pass(
    const float* __restrict__ u, const int* __restrict__ src,
    const int* __restrict__ dst, const float* __restrict__ v, float* s, int E)
{
    int e = blockIdx.x * blockDim.x + threadIdx.x;
    if (e >= E) return;
    atomicAdd(&s[src[e]], expf(u[e] + v[dst[e]]));
}
__global__ __launch_bounds__(256) void node_pass(
    const int* __restrict__ dest_mask, float* v, float* s, int N)
{
    int n = blockIdx.x * blockDim.x + threadIdx.x;
    if (n >= N) return;
    float sv = s[n];
    v[n] = dest_mask[n] ? 0.0f : (sv > 0.0f ? logf(sv) : NEGV);
    s[n] = 0.0f;
}

// ---------------- host ----------------
extern "C" void kernel_launch(void* const* d_in, const int* in_sizes, int n_in,
                              void* d_out, int out_size, void* d_ws, size_t ws_size,
                              hipStream_t stream)
{
    const float* feats     = (const float*)d_in[0];
    const int*   dest_mask = (const int*)d_in[1];
    const int*   edge_index= (const int*)d_in[2];
    const float* weight    = (const float*)d_in[5];
    const float* bias      = (const float*)d_in[6];

    const int F = in_sizes[5];
    const int E = in_sizes[2] / 2;
    const int N = in_sizes[1];

    const int* src = edge_index;
    const int* dst = edge_index + E;

    float* out   = (float*)d_out;
    float* value = out;
    float* util  = out + N;
    float* prob  = out + (size_t)N + (size_t)E;

    const int eb = (E + 255) / 256;
    const int nb = (N + 255) / 256;

    // K1: util / u
    if (F == 64) {
        const int half = (E + 1) / 2;
        long long tt = (long long)half * 16;
        int blocks = (int)((tt + 255) / 256);
        util_kernel64<<<blocks, 256, 0, stream>>>(feats, weight, bias, util, E, half);
    } else {
        util_kernel<<<eb, 256, 0, stream>>>(feats, weight, bias, util, E, F);
    }

    const int W = (N + NBUCK - 1) / NBUCK;

    // ws layout: hists(B1*NBUCK) | bstarts(NBUCK+2, pad->8B) | edg(int2 E) |
    //            row_ptr(N+1) | ewa(N) | ewb(N) | flags(N_ITERS+1)
    const size_t need_words = (size_t)B1 * NBUCK + (NBUCK + 2)
                            + 2 * (size_t)E + 3 * (size_t)N + 1 + (N_ITERS + 1);
    const size_t need_bytes = need_words * 4;
    const bool pack_ok = (N < (1 << 20)) && (W <= (1 << 12));

    if (d_ws != nullptr && ws_size >= need_bytes && pack_ok) {
        int*   hists   = (int*)d_ws;
        int*   bstarts = hists + (size_t)B1 * NBUCK;
        int2*  edg     = (int2*)(bstarts + (NBUCK + 2));
        int*   row_ptr = (int*)(edg + E);
        float* ewa     = (float*)(row_ptr + (N + 1));
        float* ewb     = ewa + N;
        int*   flags   = (int*)(ewb + N);

        const int chunk = (E + B1 - 1) / B1;
        const size_t fine_lds = (size_t)(2 * CAP + W + 8) * 4;

        bucket_count  <<<B1, 256, 0, stream>>>(src, hists, E, W, chunk);
        bucket_scan   <<<1, NBUCK, 0, stream>>>(hists, bstarts, flags, E);
        bucket_scatter<<<B1, 256, 0, stream>>>(src, dst, util, hists, edg, E, W, chunk);
        fine_sort     <<<NBUCK, 256, fine_lds, stream>>>(
            bstarts, edg, row_ptr, dest_mask, ewa, N, E, W);

        const int gb = ((N * 32) + 255) / 256;   // 32 lanes per node
        float* cur = ewa;
        float* nxt = ewb;
        for (int it = 1; it <= N_ITERS - 1; ++it) {
            const int* fp  = flags + (it - 1);
            const int* fp2 = flags + ((it >= 2) ? (it - 2) : 0);
            iter_exp_conv<<<gb, 256, 0, stream>>>(
                row_ptr, edg, dest_mask, cur, nxt, fp, fp2, flags + it, N);
            float* t = cur; cur = nxt; nxt = t;
        }
        final_exp_conv<<<gb, 256, 0, stream>>>(
            row_ptr, edg, dest_mask, cur, value, flags + (N_ITERS - 1), N);

        prob_kernel<<<eb, 256, 0, stream>>>(util, src, dst, value, prob, E);
    } else {
        float* s = prob;
        init_pass<<<nb, 256, 0, stream>>>(dest_mask, value, s, N);
        for (int it = 0; it < N_ITERS; ++it) {
            edge_pass<<<eb, 256, 0, stream>>>(util, src, dst, value, s, E);
            node_pass<<<nb, 256, 0, stream>>>(dest_mask, value, s, N);
        }
        prob_kernel<<<eb, 256, 0, stream>>>(util, src, dst, value, prob, E);
    }
}

// Round 10
// 438.931 us; speedup vs baseline: 1.9071x; 1.9071x over previous
//
#include <hip/hip_runtime.h>

#define NEGV (-1000000000.0f)
#define N_ITERS 32
#define NBUCK 512
#define B1 256
#define CAP 12288

// ---------------- util (F==64): 16 lanes per row, fully coalesced (round-8 proven) ----
__global__ __launch_bounds__(256) void util_kernel64(
    const float* __restrict__ feats, const float* __restrict__ weight,
    const float* __restrict__ bias, float* __restrict__ u, int E)
{
    int tid = blockIdx.x * blockDim.x + threadIdx.x;
    int e = tid >> 4;
    int l = tid & 15;
    if (e >= E) return;
    float4 fv = *reinterpret_cast<const float4*>(feats + (size_t)e * 64 + l * 4);
    float4 wv = *reinterpret_cast<const float4*>(weight + l * 4);
    float acc = fv.x * wv.x + fv.y * wv.y + fv.z * wv.z + fv.w * wv.w;
    acc += __shfl_xor(acc, 8, 16);
    acc += __shfl_xor(acc, 4, 16);
    acc += __shfl_xor(acc, 2, 16);
    acc += __shfl_xor(acc, 1, 16);
    if (l == 0) {
        acc += bias[0];
        u[e] = fminf(fmaxf(acc, -100.0f), -1e-6f);
    }
}

// ---------------- util generic fallback ----------------
__global__ __launch_bounds__(256) void util_kernel(
    const float* __restrict__ feats, const float* __restrict__ weight,
    const float* __restrict__ bias, float* __restrict__ u,
    int E, int F)
{
    int e = blockIdx.x * blockDim.x + threadIdx.x;
    if (e >= E) return;
    const float* row = feats + (size_t)e * (size_t)F;
    float acc = 0.0f;
    for (int f = 0; f < F; f += 4) {
        float4 fv = *reinterpret_cast<const float4*>(row + f);
        acc += fv.x * weight[f + 0];
        acc += fv.y * weight[f + 1];
        acc += fv.z * weight[f + 2];
        acc += fv.w * weight[f + 3];
    }
    acc += bias[0];
    acc = fminf(fmaxf(acc, -100.0f), -1e-6f);
    u[e] = acc;
}

// ---------------- pass 1: per-block coarse-bucket histogram (LDS) ----------------
__global__ __launch_bounds__(256) void bucket_count(
    const int* __restrict__ src, int* __restrict__ hists,
    int E, int W, int chunk)
{
    __shared__ int h[NBUCK];
    for (int i = threadIdx.x; i < NBUCK; i += 256) h[i] = 0;
    __syncthreads();
    const int lo = blockIdx.x * chunk;
    const int hi = min(E, lo + chunk);
    for (int e = lo + threadIdx.x; e < hi; e += 256) {
        unsigned k = (unsigned)src[e] / (unsigned)W;
        atomicAdd(&h[k], 1);
    }
    __syncthreads();
    for (int i = threadIdx.x; i < NBUCK; i += 256)
        hists[blockIdx.x * NBUCK + i] = h[i];
}

// ---------------- pass 2: scan + flags init ----------------
__global__ __launch_bounds__(NBUCK) void bucket_scan(
    int* __restrict__ hists, int* __restrict__ bstarts,
    int* __restrict__ flags, int E)
{
    __shared__ int tot[NBUCK];
    __shared__ int sc[NBUCK];
    const int k = threadIdx.x;
    if (k <= N_ITERS) flags[k] = (k == 0) ? 1 : 0;
    int sum = 0;
    for (int b = 0; b < B1; ++b) sum += hists[b * NBUCK + k];
    tot[k] = sum;
    sc[k] = sum;
    __syncthreads();
    for (int off = 1; off < NBUCK; off <<= 1) {
        int v = sc[k];
        if (k >= off) v += sc[k - off];
        __syncthreads();
        sc[k] = v;
        __syncthreads();
    }
    const int start = sc[k] - tot[k];
    bstarts[k] = start;
    if (k == NBUCK - 1) bstarts[NBUCK] = E;
    int run = start;
    for (int b = 0; b < B1; ++b) {
        int c = hists[b * NBUCK + k];
        hists[b * NBUCK + k] = run;
        run += c;
    }
}

// ---------------- pass 3: scatter into coarse buckets; edg = {packed, exp(u) bits} -----
__global__ __launch_bounds__(256) void bucket_scatter(
    const int* __restrict__ src, const int* __restrict__ dst,
    const float* __restrict__ u, const int* __restrict__ hists,
    int2* __restrict__ edg, int E, int W, int chunk)
{
    __shared__ int cur[NBUCK];
    for (int i = threadIdx.x; i < NBUCK; i += 256)
        cur[i] = hists[blockIdx.x * NBUCK + i];
    __syncthreads();
    const int lo = blockIdx.x * chunk;
    const int hi = min(E, lo + chunk);
    for (int e = lo + threadIdx.x; e < hi; e += 256) {
        int s = src[e];
        unsigned k = (unsigned)s / (unsigned)W;
        int pos = atomicAdd(&cur[k], 1);
        unsigned sl = (unsigned)s - k * (unsigned)W;
        int2 rec;
        rec.x = (int)((sl << 20) | (unsigned)dst[e]);
        rec.y = __float_as_int(expf(u[e]));
        edg[pos] = rec;
    }
}

// ---------------- pass 4: fine sort within bucket + ew0 init ----------------
__global__ __launch_bounds__(256) void fine_sort(
    const int* __restrict__ bstarts, int2* __restrict__ edg,
    int* __restrict__ row_ptr, const int* __restrict__ dest_mask,
    float* __restrict__ ew0, int N, int E, int W)
{
    extern __shared__ int smem[];
    int* pks = smem;
    int* ubs = smem + CAP;
    int* fh  = smem + 2 * CAP;

    const int k  = blockIdx.x;
    const int lo = k * W;
    const int nn = min(N, lo + W) - lo;
    if (k == 0 && threadIdx.x == 0) row_ptr[N] = E;
    if (nn <= 0) return;

    for (int i = threadIdx.x; i < nn; i += blockDim.x)
        ew0[lo + i] = dest_mask[lo + i] ? 1.0f : 0.0f;

    const int bs  = bstarts[k];
    const int be  = bstarts[k + 1];
    const int cnt = be - bs;

    int ldcnt = min(cnt, CAP);
    for (int i = threadIdx.x; i < ldcnt; i += blockDim.x) {
        int2 r = edg[bs + i];
        pks[i] = r.x;
        ubs[i] = r.y;
    }
    for (int i = threadIdx.x; i < nn; i += blockDim.x) fh[i] = 0;
    __syncthreads();

    for (int i = threadIdx.x; i < ldcnt; i += blockDim.x)
        atomicAdd(&fh[((unsigned)pks[i]) >> 20], 1);
    __syncthreads();

    if (threadIdx.x == 0) {
        int run = bs;
        for (int i = 0; i < nn; ++i) {
            int c = fh[i];
            fh[i] = run;
            row_ptr[lo + i] = run;
            run += c;
        }
    }
    __syncthreads();

    for (int i = threadIdx.x; i < ldcnt; i += blockDim.x) {
        int w = pks[i];
        int pos = atomicAdd(&fh[((unsigned)w) >> 20], 1);
        int2 r;
        r.x = w & 0xFFFFF;
        r.y = ubs[i];
        edg[pos] = r;
    }
}

// ---------------- one exp-domain iteration: 8 lanes/node (round-8), no-op gated -------
__global__ __launch_bounds__(256) void iter_exp_conv(
    const int* __restrict__ row_ptr, const int2* __restrict__ edg,
    const int* __restrict__ dest_mask,
    const float* __restrict__ ew, float* __restrict__ ew_new,
    const int* __restrict__ flag_prev, const int* __restrict__ flag_prev2,
    int* __restrict__ flag_cur, int N)
{
    __shared__ int blk_changed;
    int tid = blockIdx.x * blockDim.x + threadIdx.x;

    if (*flag_prev == 0) {
        if (*flag_prev2 == 0) return;          // buffers already identical: no-op
        if (tid < N) ew_new[tid] = ew[tid];    // first converged iter: equalize once
        return;
    }

    if (threadIdx.x == 0) blk_changed = 0;
    __syncthreads();

    int n = tid >> 3;
    int lane8 = tid & 7;
    if (n < N) {
        int rs = row_ptr[n];
        int re = row_ptr[n + 1];
        float s = 0.0f;
        for (int j = rs + lane8; j < re; j += 8) {
            int2 r = edg[j];
            s += __int_as_float(r.y) * ew[r.x];
        }
        s += __shfl_xor(s, 4, 8);
        s += __shfl_xor(s, 2, 8);
        s += __shfl_xor(s, 1, 8);
        if (lane8 == 0) {
            float nv = dest_mask[n] ? 1.0f : s;
            ew_new[n] = nv;
            if (__float_as_int(nv) != __float_as_int(ew[n])) blk_changed = 1;
        }
    }
    __syncthreads();
    if (threadIdx.x == 0 && blk_changed) atomicOr(flag_cur, 1);
}

// ---------------- final: one more iteration then back to log domain ----------------
__global__ __launch_bounds__(256) void final_exp_conv(
    const int* __restrict__ row_ptr, const int2* __restrict__ edg,
    const int* __restrict__ dest_mask,
    const float* __restrict__ ew, float* __restrict__ value,
    const int* __restrict__ flag_prev, int N)
{
    int tid = blockIdx.x * blockDim.x + threadIdx.x;

    if (*flag_prev == 0) {
        if (tid < N) {
            float s = ew[tid];
            value[tid] = dest_mask[tid] ? 0.0f : (s > 0.0f ? logf(s) : NEGV);
        }
        return;
    }

    int n = tid >> 3;
    int lane8 = tid & 7;
    if (n >= N) return;
    int rs = row_ptr[n];
    int re = row_ptr[n + 1];
    float s = 0.0f;
    for (int j = rs + lane8; j < re; j += 8) {
        int2 r = edg[j];
        s += __int_as_float(r.y) * ew[r.x];
    }
    s += __shfl_xor(s, 4, 8);
    s += __shfl_xor(s, 2, 8);
    s += __shfl_xor(s, 1, 8);
    if (lane8 == 0)
        value[n] = dest_mask[n] ? 0.0f : (s > 0.0f ? logf(s) : NEGV);
}

// ---------------- prob = exp((u + v[dst]) - v[src]) ----------------
__global__ __launch_bounds__(256) void prob_kernel(
    const float* __restrict__ u, const int* __restrict__ src,
    const int* __restrict__ dst, const float* __restrict__ v,
    float* __restrict__ prob, int E)
{
    int e = blockIdx.x * blockDim.x + threadIdx.x;
    if (e >= E) return;
    prob[e] = expf((u[e] + v[dst[e]]) - v[src[e]]);
}

// ================= zero-workspace fallback (atomic multi-launch path) ================
__global__ __launch_bounds__(256) void init_pass(
    const int* __restrict__ dest_mask, float* v, float* s, int N)
{
    int n = blockIdx.x * blockDim.x + threadIdx.x;
    if (n >= N) return;
    v[n] = dest_mask[n] ? 0.0f : NEGV;
    s[n] = 0.0f;
}
__global__ __launch_bounds__(256) void edge_pass(
    const float* __restrict__ u, const int* __restrict__ src,
    const int* __restrict__ dst, const float* __restrict__ v, float* s, int E)
{
    int e = blockIdx.x * blockDim.x + threadIdx.x;
    if (e >= E) return;
    atomicAdd(&s[src[e]], expf(u[e] + v[dst[e]]));
}
__global__ __launch_bounds__(256) void node_pass(
    const int* __restrict__ dest_mask, float* v, float* s, int N)
{
    int n = blockIdx.x * blockDim.x + threadIdx.x;
    if (n >= N) return;
    float sv = s[n];
    v[n] = dest_mask[n] ? 0.0f : (sv > 0.0f ? logf(sv) : NEGV);
    s[n] = 0.0f;
}

// ---------------- host ----------------
extern "C" void kernel_launch(void* const* d_in, const int* in_sizes, int n_in,
                              void* d_out, int out_size, void* d_ws, size_t ws_size,
                              hipStream_t stream)
{
    const float* feats     = (const float*)d_in[0];
    const int*   dest_mask = (const int*)d_in[1];
    const int*   edge_index= (const int*)d_in[2];
    const float* weight    = (const float*)d_in[5];
    const float* bias      = (const float*)d_in[6];

    const int F = in_sizes[5];
    const int E = in_sizes[2] / 2;
    const int N = in_sizes[1];

    const int* src = edge_index;
    const int* dst = edge_index + E;

    float* out   = (float*)d_out;
    float* value = out;
    float* util  = out + N;
    float* prob  = out + (size_t)N + (size_t)E;

    const int eb = (E + 255) / 256;
    const int nb = (N + 255) / 256;

    // K1: util / u (round-8 single-row version)
    if (F == 64) {
        long long tt = (long long)E * 16;
        int blocks = (int)((tt + 255) / 256);
        util_kernel64<<<blocks, 256, 0, stream>>>(feats, weight, bias, util, E);
    } else {
        util_kernel<<<eb, 256, 0, stream>>>(feats, weight, bias, util, E, F);
    }

    const int W = (N + NBUCK - 1) / NBUCK;

    // ws layout: hists(B1*NBUCK) | bstarts(NBUCK+2, pad->8B) | edg(int2 E) |
    //            row_ptr(N+1) | ewa(N) | ewb(N) | flags(N_ITERS+1)
    const size_t need_words = (size_t)B1 * NBUCK + (NBUCK + 2)
                            + 2 * (size_t)E + 3 * (size_t)N + 1 + (N_ITERS + 1);
    const size_t need_bytes = need_words * 4;
    const bool pack_ok = (N < (1 << 20)) && (W <= (1 << 12));

    if (d_ws != nullptr && ws_size >= need_bytes && pack_ok) {
        int*   hists   = (int*)d_ws;
        int*   bstarts = hists + (size_t)B1 * NBUCK;
        int2*  edg     = (int2*)(bstarts + (NBUCK + 2));
        int*   row_ptr = (int*)(edg + E);
        float* ewa     = (float*)(row_ptr + (N + 1));
        float* ewb     = ewa + N;
        int*   flags   = (int*)(ewb + N);

        const int chunk = (E + B1 - 1) / B1;
        const size_t fine_lds = (size_t)(2 * CAP + W + 8) * 4;

        bucket_count  <<<B1, 256, 0, stream>>>(src, hists, E, W, chunk);
        bucket_scan   <<<1, NBUCK, 0, stream>>>(hists, bstarts, flags, E);
        bucket_scatter<<<B1, 256, 0, stream>>>(src, dst, util, hists, edg, E, W, chunk);
        fine_sort     <<<NBUCK, 256, fine_lds, stream>>>(
            bstarts, edg, row_ptr, dest_mask, ewa, N, E, W);

        const int gb = ((N * 8) + 255) / 256;   // 8 lanes per node (round-8 proven)
        float* cur = ewa;
        float* nxt = ewb;
        for (int it = 1; it <= N_ITERS - 1; ++it) {
            const int* fp  = flags + (it - 1);
            const int* fp2 = flags + ((it >= 2) ? (it - 2) : 0);
            iter_exp_conv<<<gb, 256, 0, stream>>>(
                row_ptr, edg, dest_mask, cur, nxt, fp, fp2, flags + it, N);
            float* t = cur; cur = nxt; nxt = t;
        }
        final_exp_conv<<<gb, 256, 0, stream>>>(
            row_ptr, edg, dest_mask, cur, value, flags + (N_ITERS - 1), N);

        prob_kernel<<<eb, 256, 0, stream>>>(util, src, dst, value, prob, E);
    } else {
        float* s = prob;
        init_pass<<<nb, 256, 0, stream>>>(dest_mask, value, s, N);
        for (int it = 0; it < N_ITERS; ++it) {
            edge_pass<<<eb, 256, 0, stream>>>(util, src, dst, value, s, E);
            node_pass<<<nb, 256, 0, stream>>>(dest_mask, value, s, N);
        }
        prob_kernel<<<eb, 256, 0, stream>>>(util, src, dst, value, prob, E);
    }
}

// Round 11
// 438.864 us; speedup vs baseline: 1.9074x; 1.0002x over previous
//
#include <hip/hip_runtime.h>

#define NEGV (-1000000000.0f)
#define N_ITERS 32
#define NBUCK 512
#define B1 256
#define CAP 12288

// ---------------- util (F==64): 16 lanes per row-PAIR (adjacent), ILP=2 ----------------
// u[e] = clip(dot(feats[e], w) + b, -100, -1e-6)
__global__ __launch_bounds__(256) void util_kernel64x2(
    const float* __restrict__ feats, const float* __restrict__ weight,
    const float* __restrict__ bias, float* __restrict__ u, int E)
{
    int tid = blockIdx.x * blockDim.x + threadIdx.x;
    int g = tid >> 4;        // row-pair index
    int l = tid & 15;        // lane-in-row
    int r0 = g << 1;
    int r1 = r0 + 1;
    if (r0 >= E) return;
    float4 wv = *reinterpret_cast<const float4*>(weight + l * 4);
    const float* base = feats + (size_t)r0 * 64 + l * 4;
    float4 a = *reinterpret_cast<const float4*>(base);
    bool has2 = (r1 < E);
    float4 b = has2 ? *reinterpret_cast<const float4*>(base + 64) : a;
    float sa = a.x * wv.x + a.y * wv.y + a.z * wv.z + a.w * wv.w;
    float sb = b.x * wv.x + b.y * wv.y + b.z * wv.z + b.w * wv.w;
    // two interleaved independent 16-lane reductions
    sa += __shfl_xor(sa, 8, 16);  sb += __shfl_xor(sb, 8, 16);
    sa += __shfl_xor(sa, 4, 16);  sb += __shfl_xor(sb, 4, 16);
    sa += __shfl_xor(sa, 2, 16);  sb += __shfl_xor(sb, 2, 16);
    sa += __shfl_xor(sa, 1, 16);  sb += __shfl_xor(sb, 1, 16);
    if (l == 0) {
        float bb = bias[0];
        u[r0] = fminf(fmaxf(sa + bb, -100.0f), -1e-6f);
        if (has2) u[r1] = fminf(fmaxf(sb + bb, -100.0f), -1e-6f);
    }
}

// ---------------- util generic fallback ----------------
__global__ __launch_bounds__(256) void util_kernel(
    const float* __restrict__ feats, const float* __restrict__ weight,
    const float* __restrict__ bias, float* __restrict__ u,
    int E, int F)
{
    int e = blockIdx.x * blockDim.x + threadIdx.x;
    if (e >= E) return;
    const float* row = feats + (size_t)e * (size_t)F;
    float acc = 0.0f;
    for (int f = 0; f < F; f += 4) {
        float4 fv = *reinterpret_cast<const float4*>(row + f);
        acc += fv.x * weight[f + 0];
        acc += fv.y * weight[f + 1];
        acc += fv.z * weight[f + 2];
        acc += fv.w * weight[f + 3];
    }
    acc += bias[0];
    acc = fminf(fmaxf(acc, -100.0f), -1e-6f);
    u[e] = acc;
}

// ---------------- pass 1: per-block coarse-bucket histogram (LDS) ----------------
__global__ __launch_bounds__(256) void bucket_count(
    const int* __restrict__ src, int* __restrict__ hists,
    int E, int W, int chunk)
{
    __shared__ int h[NBUCK];
    for (int i = threadIdx.x; i < NBUCK; i += 256) h[i] = 0;
    __syncthreads();
    const int lo = blockIdx.x * chunk;
    const int hi = min(E, lo + chunk);
    for (int e = lo + threadIdx.x; e < hi; e += 256) {
        unsigned k = (unsigned)src[e] / (unsigned)W;
        atomicAdd(&h[k], 1);
    }
    __syncthreads();
    for (int i = threadIdx.x; i < NBUCK; i += 256)
        hists[blockIdx.x * NBUCK + i] = h[i];
}

// ---------------- pass 2: scan + flags init ----------------
__global__ __launch_bounds__(NBUCK) void bucket_scan(
    int* __restrict__ hists, int* __restrict__ bstarts,
    int* __restrict__ flags, int E)
{
    __shared__ int tot[NBUCK];
    __shared__ int sc[NBUCK];
    const int k = threadIdx.x;
    if (k <= N_ITERS) flags[k] = (k == 0) ? 1 : 0;
    int sum = 0;
    for (int b = 0; b < B1; ++b) sum += hists[b * NBUCK + k];
    tot[k] = sum;
    sc[k] = sum;
    __syncthreads();
    for (int off = 1; off < NBUCK; off <<= 1) {
        int v = sc[k];
        if (k >= off) v += sc[k - off];
        __syncthreads();
        sc[k] = v;
        __syncthreads();
    }
    const int start = sc[k] - tot[k];
    bstarts[k] = start;
    if (k == NBUCK - 1) bstarts[NBUCK] = E;
    int run = start;
    for (int b = 0; b < B1; ++b) {
        int c = hists[b * NBUCK + k];
        hists[b * NBUCK + k] = run;
        run += c;
    }
}

// ---------------- pass 3: scatter into coarse buckets; edg = {packed, exp(u) bits} -----
__global__ __launch_bounds__(256) void bucket_scatter(
    const int* __restrict__ src, const int* __restrict__ dst,
    const float* __restrict__ u, const int* __restrict__ hists,
    int2* __restrict__ edg, int E, int W, int chunk)
{
    __shared__ int cur[NBUCK];
    for (int i = threadIdx.x; i < NBUCK; i += 256)
        cur[i] = hists[blockIdx.x * NBUCK + i];
    __syncthreads();
    const int lo = blockIdx.x * chunk;
    const int hi = min(E, lo + chunk);
    for (int e = lo + threadIdx.x; e < hi; e += 256) {
        int s = src[e];
        unsigned k = (unsigned)s / (unsigned)W;
        int pos = atomicAdd(&cur[k], 1);
        unsigned sl = (unsigned)s - k * (unsigned)W;
        int2 rec;
        rec.x = (int)((sl << 20) | (unsigned)dst[e]);
        rec.y = __float_as_int(expf(u[e]));
        edg[pos] = rec;
    }
}

// ---------------- pass 4: fine sort within bucket + ew0 init ----------------
__global__ __launch_bounds__(256) void fine_sort(
    const int* __restrict__ bstarts, int2* __restrict__ edg,
    int* __restrict__ row_ptr, const int* __restrict__ dest_mask,
    float* __restrict__ ew0, int N, int E, int W)
{
    extern __shared__ int smem[];
    int* pks = smem;
    int* ubs = smem + CAP;
    int* fh  = smem + 2 * CAP;

    const int k  = blockIdx.x;
    const int lo = k * W;
    const int nn = min(N, lo + W) - lo;
    if (k == 0 && threadIdx.x == 0) row_ptr[N] = E;
    if (nn <= 0) return;

    for (int i = threadIdx.x; i < nn; i += blockDim.x)
        ew0[lo + i] = dest_mask[lo + i] ? 1.0f : 0.0f;

    const int bs  = bstarts[k];
    const int be  = bstarts[k + 1];
    const int cnt = be - bs;

    int ldcnt = min(cnt, CAP);
    for (int i = threadIdx.x; i < ldcnt; i += blockDim.x) {
        int2 r = edg[bs + i];
        pks[i] = r.x;
        ubs[i] = r.y;
    }
    for (int i = threadIdx.x; i < nn; i += blockDim.x) fh[i] = 0;
    __syncthreads();

    for (int i = threadIdx.x; i < ldcnt; i += blockDim.x)
        atomicAdd(&fh[((unsigned)pks[i]) >> 20], 1);
    __syncthreads();

    if (threadIdx.x == 0) {
        int run = bs;
        for (int i = 0; i < nn; ++i) {
            int c = fh[i];
            fh[i] = run;
            row_ptr[lo + i] = run;
            run += c;
        }
    }
    __syncthreads();

    for (int i = threadIdx.x; i < ldcnt; i += blockDim.x) {
        int w = pks[i];
        int pos = atomicAdd(&fh[((unsigned)w) >> 20], 1);
        int2 r;
        r.x = w & 0xFFFFF;
        r.y = ubs[i];
        edg[pos] = r;
    }
}

// ---------------- one exp-domain iteration: 8 lanes/node, no-op gated -------
__global__ __launch_bounds__(256) void iter_exp_conv(
    const int* __restrict__ row_ptr, const int2* __restrict__ edg,
    const int* __restrict__ dest_mask,
    const float* __restrict__ ew, float* __restrict__ ew_new,
    const int* __restrict__ flag_prev, const int* __restrict__ flag_prev2,
    int* __restrict__ flag_cur, int N)
{
    __shared__ int blk_changed;
    int tid = blockIdx.x * blockDim.x + threadIdx.x;

    if (*flag_prev == 0) {
        if (*flag_prev2 == 0) return;          // buffers already identical: no-op
        if (tid < N) ew_new[tid] = ew[tid];    // first converged iter: equalize once
        return;
    }

    if (threadIdx.x == 0) blk_changed = 0;
    __syncthreads();

    int n = tid >> 3;
    int lane8 = tid & 7;
    if (n < N) {
        int rs = row_ptr[n];
        int re = row_ptr[n + 1];
        float s = 0.0f;
        for (int j = rs + lane8; j < re; j += 8) {
            int2 r = edg[j];
            s += __int_as_float(r.y) * ew[r.x];
        }
        s += __shfl_xor(s, 4, 8);
        s += __shfl_xor(s, 2, 8);
        s += __shfl_xor(s, 1, 8);
        if (lane8 == 0) {
            float nv = dest_mask[n] ? 1.0f : s;
            ew_new[n] = nv;
            if (__float_as_int(nv) != __float_as_int(ew[n])) blk_changed = 1;
        }
    }
    __syncthreads();
    if (threadIdx.x == 0 && blk_changed) atomicOr(flag_cur, 1);
}

// ---------------- final: one more iteration then back to log domain ----------------
__global__ __launch_bounds__(256) void final_exp_conv(
    const int* __restrict__ row_ptr, const int2* __restrict__ edg,
    const int* __restrict__ dest_mask,
    const float* __restrict__ ew, float* __restrict__ value,
    const int* __restrict__ flag_prev, int N)
{
    int tid = blockIdx.x * blockDim.x + threadIdx.x;

    if (*flag_prev == 0) {
        if (tid < N) {
            float s = ew[tid];
            value[tid] = dest_mask[tid] ? 0.0f : (s > 0.0f ? logf(s) : NEGV);
        }
        return;
    }

    int n = tid >> 3;
    int lane8 = tid & 7;
    if (n >= N) return;
    int rs = row_ptr[n];
    int re = row_ptr[n + 1];
    float s = 0.0f;
    for (int j = rs + lane8; j < re; j += 8) {
        int2 r = edg[j];
        s += __int_as_float(r.y) * ew[r.x];
    }
    s += __shfl_xor(s, 4, 8);
    s += __shfl_xor(s, 2, 8);
    s += __shfl_xor(s, 1, 8);
    if (lane8 == 0)
        value[n] = dest_mask[n] ? 0.0f : (s > 0.0f ? logf(s) : NEGV);
}

// ---------------- prob = exp((u + v[dst]) - v[src]) ----------------
__global__ __launch_bounds__(256) void prob_kernel(
    const float* __restrict__ u, const int* __restrict__ src,
    const int* __restrict__ dst, const float* __restrict__ v,
    float* __restrict__ prob, int E)
{
    int e = blockIdx.x * blockDim.x + threadIdx.x;
    if (e >= E) return;
    prob[e] = expf((u[e] + v[dst[e]]) - v[src[e]]);
}

// ================= zero-workspace fallback (atomic multi-launch path) ================
__global__ __launch_bounds__(256) void init_pass(
    const int* __restrict__ dest_mask, float* v, float* s, int N)
{
    int n = blockIdx.x * blockDim.x + threadIdx.x;
    if (n >= N) return;
    v[n] = dest_mask[n] ? 0.0f : NEGV;
    s[n] = 0.0f;
}
__global__ __launch_bounds__(256) void edge_pass(
    const float* __restrict__ u, const int* __restrict__ src,
    const int* __restrict__ dst, const float* __restrict__ v, float* s, int E)
{
    int e = blockIdx.x * blockDim.x + threadIdx.x;
    if (e >= E) return;
    atomicAdd(&s[src[e]], expf(u[e] + v[dst[e]]));
}
__global__ __launch_bounds__(256) void node_pass(
    const int* __restrict__ dest_mask, float* v, float* s, int N)
{
    int n = blockIdx.x * blockDim.x + threadIdx.x;
    if (n >= N) return;
    float sv = s[n];
    v[n] = dest_mask[n] ? 0.0f : (sv > 0.0f ? logf(sv) : NEGV);
    s[n] = 0.0f;
}

// ---------------- host ----------------
extern "C" void kernel_launch(void* const* d_in, const int* in_sizes, int n_in,
                              void* d_out, int out_size, void* d_ws, size_t ws_size,
                              hipStream_t stream)
{
    const float* feats     = (const float*)d_in[0];
    const int*   dest_mask = (const int*)d_in[1];
    const int*   edge_index= (const int*)d_in[2];
    const float* weight    = (const float*)d_in[5];
    const float* bias      = (const float*)d_in[6];

    const int F = in_sizes[5];
    const int E = in_sizes[2] / 2;
    const int N = in_sizes[1];

    const int* src = edge_index;
    const int* dst = edge_index + E;

    float* out   = (float*)d_out;
    float* value = out;
    float* util  = out + N;
    float* prob  = out + (size_t)N + (size_t)E;

    const int eb = (E + 255) / 256;
    const int nb = (N + 255) / 256;

    // K1: util / u — adjacent-row ILP=2 when F==64
    if (F == 64) {
        const int pairs = (E + 1) / 2;
        long long tt = (long long)pairs * 16;
        int blocks = (int)((tt + 255) / 256);
        util_kernel64x2<<<blocks, 256, 0, stream>>>(feats, weight, bias, util, E);
    } else {
        util_kernel<<<eb, 256, 0, stream>>>(feats, weight, bias, util, E, F);
    }

    const int W = (N + NBUCK - 1) / NBUCK;

    // ws layout: hists(B1*NBUCK) | bstarts(NBUCK+2, pad->8B) | edg(int2 E) |
    //            row_ptr(N+1) | ewa(N) | ewb(N) | flags(N_ITERS+1)
    const size_t need_words = (size_t)B1 * NBUCK + (NBUCK + 2)
                            + 2 * (size_t)E + 3 * (size_t)N + 1 + (N_ITERS + 1);
    const size_t need_bytes = need_words * 4;
    const bool pack_ok = (N < (1 << 20)) && (W <= (1 << 12));

    if (d_ws != nullptr && ws_size >= need_bytes && pack_ok) {
        int*   hists   = (int*)d_ws;
        int*   bstarts = hists + (size_t)B1 * NBUCK;
        int2*  edg     = (int2*)(bstarts + (NBUCK + 2));
        int*   row_ptr = (int*)(edg + E);
        float* ewa     = (float*)(row_ptr + (N + 1));
        float* ewb     = ewa + N;
        int*   flags   = (int*)(ewb + N);

        const int chunk = (E + B1 - 1) / B1;
        const size_t fine_lds = (size_t)(2 * CAP + W + 8) * 4;

        bucket_count  <<<B1, 256, 0, stream>>>(src, hists, E, W, chunk);
        bucket_scan   <<<1, NBUCK, 0, stream>>>(hists, bstarts, flags, E);
        bucket_scatter<<<B1, 256, 0, stream>>>(src, dst, util, hists, edg, E, W, chunk);
        fine_sort     <<<NBUCK, 256, fine_lds, stream>>>(
            bstarts, edg, row_ptr, dest_mask, ewa, N, E, W);

        const int gb = ((N * 8) + 255) / 256;   // 8 lanes per node
        float* cur = ewa;
        float* nxt = ewb;
        for (int it = 1; it <= N_ITERS - 1; ++it) {
            const int* fp  = flags + (it - 1);
            const int* fp2 = flags + ((it >= 2) ? (it - 2) : 0);
            iter_exp_conv<<<gb, 256, 0, stream>>>(
                row_ptr, edg, dest_mask, cur, nxt, fp, fp2, flags + it, N);
            float* t = cur; cur = nxt; nxt = t;
        }
        final_exp_conv<<<gb, 256, 0, stream>>>(
            row_ptr, edg, dest_mask, cur, value, flags + (N_ITERS - 1), N);

        prob_kernel<<<eb, 256, 0, stream>>>(util, src, dst, value, prob, E);
    } else {
        float* s = prob;
        init_pass<<<nb, 256, 0, stream>>>(dest_mask, value, s, N);
        for (int it = 0; it < N_ITERS; ++it) {
            edge_pass<<<eb, 256, 0, stream>>>(util, src, dst, value, s, E);
            node_pass<<<nb, 256, 0, stream>>>(dest_mask, value, s, N);
        }
        prob_kernel<<<eb, 256, 0, stream>>>(util, src, dst, value, prob, E);
    }
}

// Round 12
// 434.698 us; speedup vs baseline: 1.9257x; 1.0096x over previous
//
#include <hip/hip_runtime.h>

#define NEGV (-1000000000.0f)
#define N_ITERS 32
#define NBUCK 512
#define B1 256
#define CAP 12288

// ---------------- util (F==64): grid-stride, 16 lanes/row, 2048 persistent blocks -----
// u[e] = clip(dot(feats[e], w) + b, -100, -1e-6)
__global__ __launch_bounds__(256) void util_kernel64gs(
    const float* __restrict__ feats, const float* __restrict__ weight,
    const float* __restrict__ bias, float* __restrict__ u, int E)
{
    int tid = blockIdx.x * blockDim.x + threadIdx.x;
    int l = tid & 15;                       // lane-in-row
    int g = tid >> 4;                       // group id
    int ngroups = (gridDim.x * blockDim.x) >> 4;
    float4 wv = *reinterpret_cast<const float4*>(weight + l * 4);
    float bb = bias[0];
    #pragma unroll 2
    for (int e = g; e < E; e += ngroups) {
        float4 fv = *reinterpret_cast<const float4*>(feats + (size_t)e * 64 + l * 4);
        float s = fv.x * wv.x + fv.y * wv.y + fv.z * wv.z + fv.w * wv.w;
        s += __shfl_xor(s, 8, 16);
        s += __shfl_xor(s, 4, 16);
        s += __shfl_xor(s, 2, 16);
        s += __shfl_xor(s, 1, 16);
        if (l == 0)
            u[e] = fminf(fmaxf(s + bb, -100.0f), -1e-6f);
    }
}

// ---------------- util generic fallback ----------------
__global__ __launch_bounds__(256) void util_kernel(
    const float* __restrict__ feats, const float* __restrict__ weight,
    const float* __restrict__ bias, float* __restrict__ u,
    int E, int F)
{
    int e = blockIdx.x * blockDim.x + threadIdx.x;
    if (e >= E) return;
    const float* row = feats + (size_t)e * (size_t)F;
    float acc = 0.0f;
    for (int f = 0; f < F; f += 4) {
        float4 fv = *reinterpret_cast<const float4*>(row + f);
        acc += fv.x * weight[f + 0];
        acc += fv.y * weight[f + 1];
        acc += fv.z * weight[f + 2];
        acc += fv.w * weight[f + 3];
    }
    acc += bias[0];
    acc = fminf(fmaxf(acc, -100.0f), -1e-6f);
    u[e] = acc;
}

// ---------------- pass 1: per-block coarse-bucket histogram (LDS) ----------------
__global__ __launch_bounds__(256) void bucket_count(
    const int* __restrict__ src, int* __restrict__ hists,
    int E, int W, int chunk)
{
    __shared__ int h[NBUCK];
    for (int i = threadIdx.x; i < NBUCK; i += 256) h[i] = 0;
    __syncthreads();
    const int lo = blockIdx.x * chunk;
    const int hi = min(E, lo + chunk);
    for (int e = lo + threadIdx.x; e < hi; e += 256) {
        unsigned k = (unsigned)src[e] / (unsigned)W;
        atomicAdd(&h[k], 1);
    }
    __syncthreads();
    for (int i = threadIdx.x; i < NBUCK; i += 256)
        hists[blockIdx.x * NBUCK + i] = h[i];
}

// ---------------- pass 2: scan + flags init ----------------
__global__ __launch_bounds__(NBUCK) void bucket_scan(
    int* __restrict__ hists, int* __restrict__ bstarts,
    int* __restrict__ flags, int E)
{
    __shared__ int tot[NBUCK];
    __shared__ int sc[NBUCK];
    const int k = threadIdx.x;
    if (k <= N_ITERS) flags[k] = (k == 0) ? 1 : 0;
    int sum = 0;
    for (int b = 0; b < B1; ++b) sum += hists[b * NBUCK + k];
    tot[k] = sum;
    sc[k] = sum;
    __syncthreads();
    for (int off = 1; off < NBUCK; off <<= 1) {
        int v = sc[k];
        if (k >= off) v += sc[k - off];
        __syncthreads();
        sc[k] = v;
        __syncthreads();
    }
    const int start = sc[k] - tot[k];
    bstarts[k] = start;
    if (k == NBUCK - 1) bstarts[NBUCK] = E;
    int run = start;
    for (int b = 0; b < B1; ++b) {
        int c = hists[b * NBUCK + k];
        hists[b * NBUCK + k] = run;
        run += c;
    }
}

// ---------------- pass 3: scatter into coarse buckets; edg = {packed, exp(u) bits} -----
__global__ __launch_bounds__(256) void bucket_scatter(
    const int* __restrict__ src, const int* __restrict__ dst,
    const float* __restrict__ u, const int* __restrict__ hists,
    int2* __restrict__ edg, int E, int W, int chunk)
{
    __shared__ int cur[NBUCK];
    for (int i = threadIdx.x; i < NBUCK; i += 256)
        cur[i] = hists[blockIdx.x * NBUCK + i];
    __syncthreads();
    const int lo = blockIdx.x * chunk;
    const int hi = min(E, lo + chunk);
    for (int e = lo + threadIdx.x; e < hi; e += 256) {
        int s = src[e];
        unsigned k = (unsigned)s / (unsigned)W;
        int pos = atomicAdd(&cur[k], 1);
        unsigned sl = (unsigned)s - k * (unsigned)W;
        int2 rec;
        rec.x = (int)((sl << 20) | (unsigned)dst[e]);
        rec.y = __float_as_int(expf(u[e]));
        edg[pos] = rec;
    }
}

// ---------------- pass 4: fine sort within bucket + ew0 init ----------------
__global__ __launch_bounds__(256) void fine_sort(
    const int* __restrict__ bstarts, int2* __restrict__ edg,
    int* __restrict__ row_ptr, const int* __restrict__ dest_mask,
    float* __restrict__ ew0, int N, int E, int W)
{
    extern __shared__ int smem[];
    int* pks = smem;
    int* ubs = smem + CAP;
    int* fh  = smem + 2 * CAP;

    const int k  = blockIdx.x;
    const int lo = k * W;
    const int nn = min(N, lo + W) - lo;
    if (k == 0 && threadIdx.x == 0) row_ptr[N] = E;
    if (nn <= 0) return;

    for (int i = threadIdx.x; i < nn; i += blockDim.x)
        ew0[lo + i] = dest_mask[lo + i] ? 1.0f : 0.0f;

    const int bs  = bstarts[k];
    const int be  = bstarts[k + 1];
    const int cnt = be - bs;

    int ldcnt = min(cnt, CAP);
    for (int i = threadIdx.x; i < ldcnt; i += blockDim.x) {
        int2 r = edg[bs + i];
        pks[i] = r.x;
        ubs[i] = r.y;
    }
    for (int i = threadIdx.x; i < nn; i += blockDim.x) fh[i] = 0;
    __syncthreads();

    for (int i = threadIdx.x; i < ldcnt; i += blockDim.x)
        atomicAdd(&fh[((unsigned)pks[i]) >> 20], 1);
    __syncthreads();

    if (threadIdx.x == 0) {
        int run = bs;
        for (int i = 0; i < nn; ++i) {
            int c = fh[i];
            fh[i] = run;
            row_ptr[lo + i] = run;
            run += c;
        }
    }
    __syncthreads();

    for (int i = threadIdx.x; i < ldcnt; i += blockDim.x) {
        int w = pks[i];
        int pos = atomicAdd(&fh[((unsigned)w) >> 20], 1);
        int2 r;
        r.x = w & 0xFFFFF;
        r.y = ubs[i];
        edg[pos] = r;
    }
}

// ---------------- one exp-domain iteration: 8 lanes/node, no-op gated -------
__global__ __launch_bounds__(256) void iter_exp_conv(
    const int* __restrict__ row_ptr, const int2* __restrict__ edg,
    const int* __restrict__ dest_mask,
    const float* __restrict__ ew, float* __restrict__ ew_new,
    const int* __restrict__ flag_prev, const int* __restrict__ flag_prev2,
    int* __restrict__ flag_cur, int N)
{
    __shared__ int blk_changed;
    int tid = blockIdx.x * blockDim.x + threadIdx.x;

    if (*flag_prev == 0) {
        if (*flag_prev2 == 0) return;          // buffers already identical: no-op
        if (tid < N) ew_new[tid] = ew[tid];    // first converged iter: equalize once
        return;
    }

    if (threadIdx.x == 0) blk_changed = 0;
    __syncthreads();

    int n = tid >> 3;
    int lane8 = tid & 7;
    if (n < N) {
        int rs = row_ptr[n];
        int re = row_ptr[n + 1];
        float s = 0.0f;
        for (int j = rs + lane8; j < re; j += 8) {
            int2 r = edg[j];
            s += __int_as_float(r.y) * ew[r.x];
        }
        s += __shfl_xor(s, 4, 8);
        s += __shfl_xor(s, 2, 8);
        s += __shfl_xor(s, 1, 8);
        if (lane8 == 0) {
            float nv = dest_mask[n] ? 1.0f : s;
            ew_new[n] = nv;
            if (__float_as_int(nv) != __float_as_int(ew[n])) blk_changed = 1;
        }
    }
    __syncthreads();
    if (threadIdx.x == 0 && blk_changed) atomicOr(flag_cur, 1);
}

// ---------------- final: one more iteration then back to log domain ----------------
__global__ __launch_bounds__(256) void final_exp_conv(
    const int* __restrict__ row_ptr, const int2* __restrict__ edg,
    const int* __restrict__ dest_mask,
    const float* __restrict__ ew, float* __restrict__ value,
    const int* __restrict__ flag_prev, int N)
{
    int tid = blockIdx.x * blockDim.x + threadIdx.x;

    if (*flag_prev == 0) {
        if (tid < N) {
            float s = ew[tid];
            value[tid] = dest_mask[tid] ? 0.0f : (s > 0.0f ? logf(s) : NEGV);
        }
        return;
    }

    int n = tid >> 3;
    int lane8 = tid & 7;
    if (n >= N) return;
    int rs = row_ptr[n];
    int re = row_ptr[n + 1];
    float s = 0.0f;
    for (int j = rs + lane8; j < re; j += 8) {
        int2 r = edg[j];
        s += __int_as_float(r.y) * ew[r.x];
    }
    s += __shfl_xor(s, 4, 8);
    s += __shfl_xor(s, 2, 8);
    s += __shfl_xor(s, 1, 8);
    if (lane8 == 0)
        value[n] = dest_mask[n] ? 0.0f : (s > 0.0f ? logf(s) : NEGV);
}

// ---------------- prob = exp((u + v[dst]) - v[src]) ----------------
__global__ __launch_bounds__(256) void prob_kernel(
    const float* __restrict__ u, const int* __restrict__ src,
    const int* __restrict__ dst, const float* __restrict__ v,
    float* __restrict__ prob, int E)
{
    int e = blockIdx.x * blockDim.x + threadIdx.x;
    if (e >= E) return;
    prob[e] = expf((u[e] + v[dst[e]]) - v[src[e]]);
}

// ================= zero-workspace fallback (atomic multi-launch path) ================
__global__ __launch_bounds__(256) void init_pass(
    const int* __restrict__ dest_mask, float* v, float* s, int N)
{
    int n = blockIdx.x * blockDim.x + threadIdx.x;
    if (n >= N) return;
    v[n] = dest_mask[n] ? 0.0f : NEGV;
    s[n] = 0.0f;
}
__global__ __launch_bounds__(256) void edge_pass(
    const float* __restrict__ u, const int* __restrict__ src,
    const int* __restrict__ dst, const float* __restrict__ v, float* s, int E)
{
    int e = blockIdx.x * blockDim.x + threadIdx.x;
    if (e >= E) return;
    atomicAdd(&s[src[e]], expf(u[e] + v[dst[e]]));
}
__global__ __launch_bounds__(256) void node_pass(
    const int* __restrict__ dest_mask, float* v, float* s, int N)
{
    int n = blockIdx.x * blockDim.x + threadIdx.x;
    if (n >= N) return;
    float sv = s[n];
    v[n] = dest_mask[n] ? 0.0f : (sv > 0.0f ? logf(sv) : NEGV);
    s[n] = 0.0f;
}

// ---------------- host ----------------
extern "C" void kernel_launch(void* const* d_in, const int* in_sizes, int n_in,
                              void* d_out, int out_size, void* d_ws, size_t ws_size,
                              hipStream_t stream)
{
    const float* feats     = (const float*)d_in[0];
    const int*   dest_mask = (const int*)d_in[1];
    const int*   edge_index= (const int*)d_in[2];
    const float* weight    = (const float*)d_in[5];
    const float* bias      = (const float*)d_in[6];

    const int F = in_sizes[5];
    const int E = in_sizes[2] / 2;
    const int N = in_sizes[1];

    const int* src = edge_index;
    const int* dst = edge_index + E;

    float* out   = (float*)d_out;
    float* value = out;
    float* util  = out + N;
    float* prob  = out + (size_t)N + (size_t)E;

    const int eb = (E + 255) / 256;
    const int nb = (N + 255) / 256;

    // K1: util / u — grid-stride persistent blocks when F==64
    if (F == 64) {
        util_kernel64gs<<<2048, 256, 0, stream>>>(feats, weight, bias, util, E);
    } else {
        util_kernel<<<eb, 256, 0, stream>>>(feats, weight, bias, util, E, F);
    }

    const int W = (N + NBUCK - 1) / NBUCK;

    // ws layout: hists(B1*NBUCK) | bstarts(NBUCK+2, pad->8B) | edg(int2 E) |
    //            row_ptr(N+1) | ewa(N) | ewb(N) | flags(N_ITERS+1)
    const size_t need_words = (size_t)B1 * NBUCK + (NBUCK + 2)
                            + 2 * (size_t)E + 3 * (size_t)N + 1 + (N_ITERS + 1);
    const size_t need_bytes = need_words * 4;
    const bool pack_ok = (N < (1 << 20)) && (W <= (1 << 12));

    if (d_ws != nullptr && ws_size >= need_bytes && pack_ok) {
        int*   hists   = (int*)d_ws;
        int*   bstarts = hists + (size_t)B1 * NBUCK;
        int2*  edg     = (int2*)(bstarts + (NBUCK + 2));
        int*   row_ptr = (int*)(edg + E);
        float* ewa     = (float*)(row_ptr + (N + 1));
        float* ewb     = ewa + N;
        int*   flags   = (int*)(ewb + N);

        const int chunk = (E + B1 - 1) / B1;
        const size_t fine_lds = (size_t)(2 * CAP + W + 8) * 4;

        bucket_count  <<<B1, 256, 0, stream>>>(src, hists, E, W, chunk);
        bucket_scan   <<<1, NBUCK, 0, stream>>>(hists, bstarts, flags, E);
        bucket_scatter<<<B1, 256, 0, stream>>>(src, dst, util, hists, edg, E, W, chunk);
        fine_sort     <<<NBUCK, 256, fine_lds, stream>>>(
            bstarts, edg, row_ptr, dest_mask, ewa, N, E, W);

        const int gb = ((N * 8) + 255) / 256;   // 8 lanes per node
        float* cur = ewa;
        float* nxt = ewb;
        for (int it = 1; it <= N_ITERS - 1; ++it) {
            const int* fp  = flags + (it - 1);
            const int* fp2 = flags + ((it >= 2) ? (it - 2) : 0);
            iter_exp_conv<<<gb, 256, 0, stream>>>(
                row_ptr, edg, dest_mask, cur, nxt, fp, fp2, flags + it, N);
            float* t = cur; cur = nxt; nxt = t;
        }
        final_exp_conv<<<gb, 256, 0, stream>>>(
            row_ptr, edg, dest_mask, cur, value, flags + (N_ITERS - 1), N);

        prob_kernel<<<eb, 256, 0, stream>>>(util, src, dst, value, prob, E);
    } else {
        float* s = prob;
        init_pass<<<nb, 256, 0, stream>>>(dest_mask, value, s, N);
        for (int it = 0; it < N_ITERS; ++it) {
            edge_pass<<<eb, 256, 0, stream>>>(util, src, dst, value, s, E);
            node_pass<<<nb, 256, 0, stream>>>(dest_mask, value, s, N);
        }
        prob_kernel<<<eb, 256, 0, stream>>>(util, src, dst, value, prob, E);
    }
}

// Round 13
// 401.760 us; speedup vs baseline: 2.0835x; 1.0820x over previous
//
#include <hip/hip_runtime.h>

#define NEGV (-1000000000.0f)
#define N_ITERS 32
#define NBUCK 512
#define B1 256
#define REG 4096
#define CPAD 16   // cursor padding (ints) = one 64B line per bucket

// ---------------- util (F==64): grid-stride 16 lanes/row; block 0 inits cursors+flags --
__global__ __launch_bounds__(256) void util_kernel64gs(
    const float* __restrict__ feats, const float* __restrict__ weight,
    const float* __restrict__ bias, float* __restrict__ u,
    int* __restrict__ cursors, int* __restrict__ flags, int E)
{
    if (blockIdx.x == 0) {
        for (int i = threadIdx.x; i < NBUCK; i += 256)
            cursors[(size_t)i * CPAD] = i * REG;
        if (threadIdx.x <= N_ITERS)
            flags[threadIdx.x] = (threadIdx.x == 0) ? 1 : 0;
    }
    int tid = blockIdx.x * blockDim.x + threadIdx.x;
    int l = tid & 15;
    int g = tid >> 4;
    int ngroups = (gridDim.x * blockDim.x) >> 4;
    float4 wv = *reinterpret_cast<const float4*>(weight + l * 4);
    float bb = bias[0];
    for (int e = g; e < E; e += ngroups) {
        float4 fv = *reinterpret_cast<const float4*>(feats + (size_t)e * 64 + l * 4);
        float s = fv.x * wv.x + fv.y * wv.y + fv.z * wv.z + fv.w * wv.w;
        s += __shfl_xor(s, 8, 16);
        s += __shfl_xor(s, 4, 16);
        s += __shfl_xor(s, 2, 16);
        s += __shfl_xor(s, 1, 16);
        if (l == 0)
            u[e] = fminf(fmaxf(s + bb, -100.0f), -1e-6f);
    }
}

// ---------------- util generic fallback (also inits cursors+flags) ----------------
__global__ __launch_bounds__(256) void util_kernel(
    const float* __restrict__ feats, const float* __restrict__ weight,
    const float* __restrict__ bias, float* __restrict__ u,
    int* __restrict__ cursors, int* __restrict__ flags, int E, int F)
{
    if (blockIdx.x == 0) {
        for (int i = threadIdx.x; i < NBUCK; i += 256)
            cursors[(size_t)i * CPAD] = i * REG;
        if (threadIdx.x <= N_ITERS)
            flags[threadIdx.x] = (threadIdx.x == 0) ? 1 : 0;
    }
    int e = blockIdx.x * blockDim.x + threadIdx.x;
    if (e >= E) return;
    const float* row = feats + (size_t)e * (size_t)F;
    float acc = 0.0f;
    for (int f = 0; f < F; f += 4) {
        float4 fv = *reinterpret_cast<const float4*>(row + f);
        acc += fv.x * weight[f + 0];
        acc += fv.y * weight[f + 1];
        acc += fv.z * weight[f + 2];
        acc += fv.w * weight[f + 3];
    }
    acc += bias[0];
    u[e] = fminf(fmaxf(acc, -100.0f), -1e-6f);
}

// ---------------- fused scatter: LDS count -> global slice claim -> LDS-cursor scatter --
// edg[pos] = { (src_local<<20)|dst , exp(u) bits } into per-bucket region [k*REG, (k+1)*REG)
__global__ __launch_bounds__(256) void scatter_fused(
    const int* __restrict__ src, const int* __restrict__ dst,
    const float* __restrict__ u, int* __restrict__ cursors,
    int2* __restrict__ edg, int E, int W, int chunk)
{
    __shared__ int h[NBUCK];
    for (int i = threadIdx.x; i < NBUCK; i += 256) h[i] = 0;
    __syncthreads();
    const int lo = blockIdx.x * chunk;
    const int hi = min(E, lo + chunk);
    for (int e = lo + threadIdx.x; e < hi; e += 256)
        atomicAdd(&h[(unsigned)src[e] / (unsigned)W], 1);
    __syncthreads();
    for (int k = threadIdx.x; k < NBUCK; k += 256) {
        int c = h[k];
        h[k] = (c > 0) ? atomicAdd(&cursors[(size_t)k * CPAD], c) : 0;
    }
    __syncthreads();
    for (int e = lo + threadIdx.x; e < hi; e += 256) {
        int s = src[e];
        unsigned k = (unsigned)s / (unsigned)W;
        int pos = atomicAdd(&h[k], 1);
        if (pos < (int)((k + 1) * REG)) {   // drop-clamp (adversarial overflow only)
            unsigned sl = (unsigned)s - k * (unsigned)W;
            int2 rec;
            rec.x = (int)((sl << 20) | (unsigned)dst[e]);
            rec.y = __float_as_int(expf(u[e]));
            edg[pos] = rec;
        }
    }
}

// ---------------- fine sort within bucket (static 33KB LDS) + row_ptr/row_end + ew0 ----
__global__ __launch_bounds__(256) void fine_sort(
    const int* __restrict__ cursors, int2* __restrict__ edg,
    int* __restrict__ row_ptr, int* __restrict__ row_end,
    const int* __restrict__ dest_mask, float* __restrict__ ew0,
    int N, int W)
{
    __shared__ int pks[REG];
    __shared__ int ubs[REG];
    __shared__ int fh[132];

    const int k  = blockIdx.x;
    const int lo = k * W;
    const int nn = min(N, lo + W) - lo;
    if (nn <= 0) return;

    for (int i = threadIdx.x; i < nn; i += 256)
        ew0[lo + i] = dest_mask[lo + i] ? 1.0f : 0.0f;

    const int bs = k * REG;
    int cnt = cursors[(size_t)k * CPAD] - bs;
    if (cnt > REG) cnt = REG;
    if (cnt < 0) cnt = 0;

    for (int i = threadIdx.x; i < cnt; i += 256) {
        int2 r = edg[bs + i];
        pks[i] = r.x;
        ubs[i] = r.y;
    }
    for (int i = threadIdx.x; i < nn; i += 256) fh[i] = 0;
    __syncthreads();

    for (int i = threadIdx.x; i < cnt; i += 256)
        atomicAdd(&fh[((unsigned)pks[i]) >> 20], 1);
    __syncthreads();

    if (threadIdx.x == 0) {
        int run = bs;
        for (int i = 0; i < nn; ++i) {
            int c = fh[i];
            fh[i] = run;
            row_ptr[lo + i] = run;
            row_end[lo + i] = run + c;
            run += c;
        }
    }
    __syncthreads();

    for (int i = threadIdx.x; i < cnt; i += 256) {
        int w = pks[i];
        int pos = atomicAdd(&fh[((unsigned)w) >> 20], 1);
        int2 r;
        r.x = w & 0xFFFFF;
        r.y = ubs[i];
        edg[pos] = r;
    }
}

// ---------------- one exp-domain iteration: 8 lanes/node, no-op gated ----------------
__global__ __launch_bounds__(256) void iter_exp_conv(
    const int* __restrict__ row_ptr, const int* __restrict__ row_end,
    const int2* __restrict__ edg, const int* __restrict__ dest_mask,
    const float* __restrict__ ew, float* __restrict__ ew_new,
    const int* __restrict__ flag_prev, const int* __restrict__ flag_prev2,
    int* __restrict__ flag_cur, int N)
{
    __shared__ int blk_changed;
    int tid = blockIdx.x * blockDim.x + threadIdx.x;

    if (*flag_prev == 0) {
        if (*flag_prev2 == 0) return;          // buffers already identical: no-op
        if (tid < N) ew_new[tid] = ew[tid];    // first converged iter: equalize once
        return;
    }

    if (threadIdx.x == 0) blk_changed = 0;
    __syncthreads();

    int n = tid >> 3;
    int lane8 = tid & 7;
    if (n < N) {
        int rs = row_ptr[n];
        int re = row_end[n];
        float s = 0.0f;
        for (int j = rs + lane8; j < re; j += 8) {
            int2 r = edg[j];
            s += __int_as_float(r.y) * ew[r.x];
        }
        s += __shfl_xor(s, 4, 8);
        s += __shfl_xor(s, 2, 8);
        s += __shfl_xor(s, 1, 8);
        if (lane8 == 0) {
            float nv = dest_mask[n] ? 1.0f : s;
            ew_new[n] = nv;
            if (__float_as_int(nv) != __float_as_int(ew[n])) blk_changed = 1;
        }
    }
    __syncthreads();
    if (threadIdx.x == 0 && blk_changed) atomicOr(flag_cur, 1);
}

// ---------------- final: one more iteration then back to log domain ----------------
__global__ __launch_bounds__(256) void final_exp_conv(
    const int* __restrict__ row_ptr, const int* __restrict__ row_end,
    const int2* __restrict__ edg, const int* __restrict__ dest_mask,
    const float* __restrict__ ew, float* __restrict__ value,
    const int* __restrict__ flag_prev, int N)
{
    int tid = blockIdx.x * blockDim.x + threadIdx.x;

    if (*flag_prev == 0) {
        if (tid < N) {
            float s = ew[tid];
            value[tid] = dest_mask[tid] ? 0.0f : (s > 0.0f ? logf(s) : NEGV);
        }
        return;
    }

    int n = tid >> 3;
    int lane8 = tid & 7;
    if (n >= N) return;
    int rs = row_ptr[n];
    int re = row_end[n];
    float s = 0.0f;
    for (int j = rs + lane8; j < re; j += 8) {
        int2 r = edg[j];
        s += __int_as_float(r.y) * ew[r.x];
    }
    s += __shfl_xor(s, 4, 8);
    s += __shfl_xor(s, 2, 8);
    s += __shfl_xor(s, 1, 8);
    if (lane8 == 0)
        value[n] = dest_mask[n] ? 0.0f : (s > 0.0f ? logf(s) : NEGV);
}

// ---------------- prob = exp((u + v[dst]) - v[src]) ----------------
__global__ __launch_bounds__(256) void prob_kernel(
    const float* __restrict__ u, const int* __restrict__ src,
    const int* __restrict__ dst, const float* __restrict__ v,
    float* __restrict__ prob, int E)
{
    int e = blockIdx.x * blockDim.x + threadIdx.x;
    if (e >= E) return;
    prob[e] = expf((u[e] + v[dst[e]]) - v[src[e]]);
}

// ================= zero-workspace fallback (atomic multi-launch path) ================
__global__ __launch_bounds__(256) void util_plain(
    const float* __restrict__ feats, const float* __restrict__ weight,
    const float* __restrict__ bias, float* __restrict__ u, int E, int F)
{
    int e = blockIdx.x * blockDim.x + threadIdx.x;
    if (e >= E) return;
    const float* row = feats + (size_t)e * (size_t)F;
    float acc = 0.0f;
    for (int f = 0; f < F; f += 4) {
        float4 fv = *reinterpret_cast<const float4*>(row + f);
        acc += fv.x * weight[f + 0];
        acc += fv.y * weight[f + 1];
        acc += fv.z * weight[f + 2];
        acc += fv.w * weight[f + 3];
    }
    acc += bias[0];
    u[e] = fminf(fmaxf(acc, -100.0f), -1e-6f);
}
__global__ __launch_bounds__(256) void init_pass(
    const int* __restrict__ dest_mask, float* v, float* s, int N)
{
    int n = blockIdx.x * blockDim.x + threadIdx.x;
    if (n >= N) return;
    v[n] = dest_mask[n] ? 0.0f : NEGV;
    s[n] = 0.0f;
}
__global__ __launch_bounds__(256) void edge_pass(
    const float* __restrict__ u, const int* __restrict__ src,
    const int* __restrict__ dst, const float* __restrict__ v, float* s, int E)
{
    int e = blockIdx.x * blockDim.x + threadIdx.x;
    if (e >= E) return;
    atomicAdd(&s[src[e]], expf(u[e] + v[dst[e]]));
}
__global__ __launch_bounds__(256) void node_pass(
    const int* __restrict__ dest_mask, float* v, float* s, int N)
{
    int n = blockIdx.x * blockDim.x + threadIdx.x;
    if (n >= N) return;
    float sv = s[n];
    v[n] = dest_mask[n] ? 0.0f : (sv > 0.0f ? logf(sv) : NEGV);
    s[n] = 0.0f;
}

// ---------------- host ----------------
extern "C" void kernel_launch(void* const* d_in, const int* in_sizes, int n_in,
                              void* d_out, int out_size, void* d_ws, size_t ws_size,
                              hipStream_t stream)
{
    const float* feats     = (const float*)d_in[0];
    const int*   dest_mask = (const int*)d_in[1];
    const int*   edge_index= (const int*)d_in[2];
    const float* weight    = (const float*)d_in[5];
    const float* bias      = (const float*)d_in[6];

    const int F = in_sizes[5];
    const int E = in_sizes[2] / 2;
    const int N = in_sizes[1];

    const int* src = edge_index;
    const int* dst = edge_index + E;

    float* out   = (float*)d_out;
    float* value = out;
    float* util  = out + N;
    float* prob  = out + (size_t)N + (size_t)E;

    const int eb = (E + 255) / 256;
    const int nb = (N + 255) / 256;

    const int W = (N + NBUCK - 1) / NBUCK;   // nodes per bucket

    // ws layout: cursors(NBUCK*CPAD) | edg(int2 NBUCK*REG) | row_ptr(N) | row_end(N) |
    //            ewa(N) | ewb(N) | flags(N_ITERS+1)
    const size_t need_words = (size_t)NBUCK * CPAD + 2 * (size_t)NBUCK * REG
                            + 4 * (size_t)N + (N_ITERS + 1);
    const size_t need_bytes = need_words * 4;
    const bool pack_ok = (N < (1 << 20)) && (W <= 128)
                      && ((size_t)NBUCK * REG >= (size_t)E);

    if (d_ws != nullptr && ws_size >= need_bytes && pack_ok) {
        int*   cursors = (int*)d_ws;
        int2*  edg     = (int2*)(cursors + (size_t)NBUCK * CPAD);  // 32KB offset: 8B-aligned
        int*   row_ptr = (int*)(edg + (size_t)NBUCK * REG);
        int*   row_end = row_ptr + N;
        float* ewa     = (float*)(row_end + N);
        float* ewb     = ewa + N;
        int*   flags   = (int*)(ewb + N);

        // K1: util (+ cursor/flag init in block 0)
        if (F == 64) {
            util_kernel64gs<<<2048, 256, 0, stream>>>(
                feats, weight, bias, util, cursors, flags, E);
        } else {
            util_kernel<<<eb, 256, 0, stream>>>(
                feats, weight, bias, util, cursors, flags, E, F);
        }

        const int chunk = (E + B1 - 1) / B1;
        scatter_fused<<<B1, 256, 0, stream>>>(src, dst, util, cursors, edg, E, W, chunk);
        fine_sort<<<NBUCK, 256, 0, stream>>>(
            cursors, edg, row_ptr, row_end, dest_mask, ewa, N, W);

        const int gb = ((N * 8) + 255) / 256;   // 8 lanes per node
        float* cur = ewa;
        float* nxt = ewb;
        for (int it = 1; it <= N_ITERS - 1; ++it) {
            const int* fp  = flags + (it - 1);
            const int* fp2 = flags + ((it >= 2) ? (it - 2) : 0);
            iter_exp_conv<<<gb, 256, 0, stream>>>(
                row_ptr, row_end, edg, dest_mask, cur, nxt, fp, fp2, flags + it, N);
            float* t = cur; cur = nxt; nxt = t;
        }
        final_exp_conv<<<gb, 256, 0, stream>>>(
            row_ptr, row_end, edg, dest_mask, cur, value, flags + (N_ITERS - 1), N);

        prob_kernel<<<eb, 256, 0, stream>>>(util, src, dst, value, prob, E);
    } else {
        // fallback: atomic multi-launch path; s carved from prob region
        util_plain<<<eb, 256, 0, stream>>>(feats, weight, bias, util, E, F);
        float* s = prob;
        init_pass<<<nb, 256, 0, stream>>>(dest_mask, value, s, N);
        for (int it = 0; it < N_ITERS; ++it) {
            edge_pass<<<eb, 256, 0, stream>>>(util, src, dst, value, s, E);
            node_pass<<<nb, 256, 0, stream>>>(dest_mask, value, s, N);
        }
        prob_kernel<<<eb, 256, 0, stream>>>(util, src, dst, value, prob, E);
    }
}

// Round 15
// 361.563 us; speedup vs baseline: 2.3152x; 1.1112x over previous
//
#include <hip/hip_runtime.h>

#define NEGV (-1000000000.0f)
#define N_ITERS 32
#define NBUCK 512
#define B1 256
#define REG 4096
#define CPAD 16   // cursor padding (ints) = one 64B line per bucket

typedef float f32x4 __attribute__((ext_vector_type(4)));

// ---------------- util (F==64): grid-stride 16 lanes/row, NT loads; block 0 inits -----
__global__ __launch_bounds__(256) void util_kernel64gs(
    const float* __restrict__ feats, const float* __restrict__ weight,
    const float* __restrict__ bias, float* __restrict__ u,
    int* __restrict__ cursors, int* __restrict__ flags, int E)
{
    if (blockIdx.x == 0) {
        for (int i = threadIdx.x; i < NBUCK; i += 256)
            cursors[(size_t)i * CPAD] = i * REG;
        if (threadIdx.x <= N_ITERS)
            flags[threadIdx.x] = (threadIdx.x <= 1) ? 1 : 0;  // iter-1 fused: flags[1]=1
    }
    int tid = blockIdx.x * blockDim.x + threadIdx.x;
    int l = tid & 15;
    int g = tid >> 4;
    int ngroups = (gridDim.x * blockDim.x) >> 4;
    f32x4 wv = *reinterpret_cast<const f32x4*>(weight + l * 4);
    float bb = bias[0];
    for (int e = g; e < E; e += ngroups) {
        f32x4 fv = __builtin_nontemporal_load(
            reinterpret_cast<const f32x4*>(feats + (size_t)e * 64 + l * 4));
        float s = fv.x * wv.x + fv.y * wv.y + fv.z * wv.z + fv.w * wv.w;
        s += __shfl_xor(s, 8, 16);
        s += __shfl_xor(s, 4, 16);
        s += __shfl_xor(s, 2, 16);
        s += __shfl_xor(s, 1, 16);
        if (l == 0)
            u[e] = fminf(fmaxf(s + bb, -100.0f), -1e-6f);
    }
}

// ---------------- util generic fallback (also inits cursors+flags) ----------------
__global__ __launch_bounds__(256) void util_kernel(
    const float* __restrict__ feats, const float* __restrict__ weight,
    const float* __restrict__ bias, float* __restrict__ u,
    int* __restrict__ cursors, int* __restrict__ flags, int E, int F)
{
    if (blockIdx.x == 0) {
        for (int i = threadIdx.x; i < NBUCK; i += 256)
            cursors[(size_t)i * CPAD] = i * REG;
        if (threadIdx.x <= N_ITERS)
            flags[threadIdx.x] = (threadIdx.x <= 1) ? 1 : 0;
    }
    int e = blockIdx.x * blockDim.x + threadIdx.x;
    if (e >= E) return;
    const float* row = feats + (size_t)e * (size_t)F;
    float acc = 0.0f;
    for (int f = 0; f < F; f += 4) {
        float4 fv = *reinterpret_cast<const float4*>(row + f);
        acc += fv.x * weight[f + 0];
        acc += fv.y * weight[f + 1];
        acc += fv.z * weight[f + 2];
        acc += fv.w * weight[f + 3];
    }
    acc += bias[0];
    u[e] = fminf(fmaxf(acc, -100.0f), -1e-6f);
}

// ---------------- fused scatter: LDS count -> global slice claim -> LDS-cursor scatter --
__global__ __launch_bounds__(256) void scatter_fused(
    const int* __restrict__ src, const int* __restrict__ dst,
    const float* __restrict__ u, int* __restrict__ cursors,
    int2* __restrict__ edg, int E, int W, int chunk)
{
    __shared__ int h[NBUCK];
    for (int i = threadIdx.x; i < NBUCK; i += 256) h[i] = 0;
    __syncthreads();
    const int lo = blockIdx.x * chunk;
    const int hi = min(E, lo + chunk);
    for (int e = lo + threadIdx.x; e < hi; e += 256)
        atomicAdd(&h[(unsigned)src[e] / (unsigned)W], 1);
    __syncthreads();
    for (int k = threadIdx.x; k < NBUCK; k += 256) {
        int c = h[k];
        h[k] = (c > 0) ? atomicAdd(&cursors[(size_t)k * CPAD], c) : 0;
    }
    __syncthreads();
    for (int e = lo + threadIdx.x; e < hi; e += 256) {
        int s = src[e];
        unsigned k = (unsigned)s / (unsigned)W;
        int pos = atomicAdd(&h[k], 1);
        if (pos < (int)((k + 1) * REG)) {   // drop-clamp (adversarial overflow only)
            unsigned sl = (unsigned)s - k * (unsigned)W;
            int2 rec;
            rec.x = (int)((sl << 20) | (unsigned)dst[e]);
            rec.y = __float_as_int(expf(u[e]));
            edg[pos] = rec;
        }
    }
}

// ---------------- fine sort within bucket + FUSED ITERATION 1 ----------------
// Sorts bucket k's edges into CSR order, writes row_ptr/row_end, then computes
// ew1[n] = dest ? 1 : sum_j eu_j * (dest_mask[dst_j] ? 1 : 0) for its own rows
// (identical 8-lane + shfl order as iter_exp_conv => bitwise-matching values).
__global__ __launch_bounds__(256) void fine_sort(
    const int* __restrict__ cursors, int2* __restrict__ edg,
    int* __restrict__ row_ptr, int* __restrict__ row_end,
    const int* __restrict__ dest_mask, float* __restrict__ ew1,
    int N, int W)
{
    __shared__ int pks[REG];
    __shared__ int ubs[REG];
    __shared__ int fh[132];
    __shared__ int rst[132];

    const int k  = blockIdx.x;
    const int lo = k * W;
    const int nn = min(N, lo + W) - lo;
    if (nn <= 0) return;

    const int bs = k * REG;
    int cnt = cursors[(size_t)k * CPAD] - bs;
    if (cnt > REG) cnt = REG;
    if (cnt < 0) cnt = 0;

    for (int i = threadIdx.x; i < cnt; i += 256) {
        int2 r = edg[bs + i];
        pks[i] = r.x;
        ubs[i] = r.y;
    }
    for (int i = threadIdx.x; i < nn; i += 256) fh[i] = 0;
    __syncthreads();

    for (int i = threadIdx.x; i < cnt; i += 256)
        atomicAdd(&fh[((unsigned)pks[i]) >> 20], 1);
    __syncthreads();

    if (threadIdx.x == 0) {
        int run = bs;
        for (int i = 0; i < nn; ++i) {
            int c = fh[i];
            fh[i] = run;
            rst[i] = run;
            row_ptr[lo + i] = run;
            row_end[lo + i] = run + c;
            run += c;
        }
    }
    __syncthreads();

    for (int i = threadIdx.x; i < cnt; i += 256) {
        int w = pks[i];
        int pos = atomicAdd(&fh[((unsigned)w) >> 20], 1);
        int2 r;
        r.x = w & 0xFFFFF;
        r.y = ubs[i];
        edg[pos] = r;
    }
    __syncthreads();   // bucket's edg region complete (this block wrote all of it)

    // fused iteration 1 over this bucket's rows (edges L2-hot)
    const int grp   = threadIdx.x >> 3;   // 0..31
    const int lane8 = threadIdx.x & 7;
    for (int base = 0; base < nn; base += 32) {
        int ridx = base + grp;
        if (ridx < nn) {
            int n  = lo + ridx;
            int rs = rst[ridx];
            int re = fh[ridx];            // after scatter-back, fh = row end
            float s = 0.0f;
            for (int j = rs + lane8; j < re; j += 8) {
                int2 r = edg[j];
                s += __int_as_float(r.y) * (dest_mask[r.x] ? 1.0f : 0.0f);
            }
            s += __shfl_xor(s, 4, 8);
            s += __shfl_xor(s, 2, 8);
            s += __shfl_xor(s, 1, 8);
            if (lane8 == 0)
                ew1[n] = dest_mask[n] ? 1.0f : s;
        }
    }
}

// ---------------- one exp-domain iteration: 8 lanes/node, no-op gated ----------------
// flag_prev2 points at flags[it-2]; flags[it-2],flags[it-1] loaded as one int2.
__global__ __launch_bounds__(256) void iter_exp_conv(
    const int* __restrict__ row_ptr, const int* __restrict__ row_end,
    const int2* __restrict__ edg, const int* __restrict__ dest_mask,
    const float* __restrict__ ew, float* __restrict__ ew_new,
    const int* __restrict__ flag_prev2, int* __restrict__ flag_cur, int N)
{
    __shared__ int blk_changed;
    int tid = blockIdx.x * blockDim.x + threadIdx.x;

    int2 fl = *reinterpret_cast<const int2*>(flag_prev2);  // (flags[it-2], flags[it-1])
    if (fl.y == 0) {
        if (fl.x == 0) return;                 // buffers already identical: no-op
        if (tid < N) ew_new[tid] = ew[tid];    // first converged iter: equalize once
        return;
    }

    if (threadIdx.x == 0) blk_changed = 0;
    __syncthreads();

    int n = tid >> 3;
    int lane8 = tid & 7;
    if (n < N) {
        int rs = row_ptr[n];
        int re = row_end[n];
        float s = 0.0f;
        for (int j = rs + lane8; j < re; j += 8) {
            int2 r = edg[j];
            s += __int_as_float(r.y) * ew[r.x];
        }
        s += __shfl_xor(s, 4, 8);
        s += __shfl_xor(s, 2, 8);
        s += __shfl_xor(s, 1, 8);
        if (lane8 == 0) {
            float nv = dest_mask[n] ? 1.0f : s;
            ew_new[n] = nv;
            if (__float_as_int(nv) != __float_as_int(ew[n])) blk_changed = 1;
        }
    }
    __syncthreads();
    if (threadIdx.x == 0 && blk_changed) atomicOr(flag_cur, 1);
}

// ---------------- final: one more iteration then back to log domain ----------------
__global__ __launch_bounds__(256) void final_exp_conv(
    const int* __restrict__ row_ptr, const int* __restrict__ row_end,
    const int2* __restrict__ edg, const int* __restrict__ dest_mask,
    const float* __restrict__ ew, float* __restrict__ value,
    const int* __restrict__ flag_prev, int N)
{
    int tid = blockIdx.x * blockDim.x + threadIdx.x;

    if (*flag_prev == 0) {
        if (tid < N) {
            float s = ew[tid];
            value[tid] = dest_mask[tid] ? 0.0f : (s > 0.0f ? logf(s) : NEGV);
        }
        return;
    }

    int n = tid >> 3;
    int lane8 = tid & 7;
    if (n >= N) return;
    int rs = row_ptr[n];
    int re = row_end[n];
    float s = 0.0f;
    for (int j = rs + lane8; j < re; j += 8) {
        int2 r = edg[j];
        s += __int_as_float(r.y) * ew[r.x];
    }
    s += __shfl_xor(s, 4, 8);
    s += __shfl_xor(s, 2, 8);
    s += __shfl_xor(s, 1, 8);
    if (lane8 == 0)
        value[n] = dest_mask[n] ? 0.0f : (s > 0.0f ? logf(s) : NEGV);
}

// ---------------- prob = exp((u + v[dst]) - v[src]) ----------------
__global__ __launch_bounds__(256) void prob_kernel(
    const float* __restrict__ u, const int* __restrict__ src,
    const int* __restrict__ dst, const float* __restrict__ v,
    float* __restrict__ prob, int E)
{
    int e = blockIdx.x * blockDim.x + threadIdx.x;
    if (e >= E) return;
    prob[e] = expf((u[e] + v[dst[e]]) - v[src[e]]);
}

// ================= zero-workspace fallback (atomic multi-launch path) ================
__global__ __launch_bounds__(256) void util_plain(
    const float* __restrict__ feats, const float* __restrict__ weight,
    const float* __restrict__ bias, float* __restrict__ u, int E, int F)
{
    int e = blockIdx.x * blockDim.x + threadIdx.x;
    if (e >= E) return;
    const float* row = feats + (size_t)e * (size_t)F;
    float acc = 0.0f;
    for (int f = 0; f < F; f += 4) {
        float4 fv = *reinterpret_cast<const float4*>(row + f);
        acc += fv.x * weight[f + 0];
        acc += fv.y * weight[f + 1];
        acc += fv.z * weight[f + 2];
        acc += fv.w * weight[f + 3];
    }
    acc += bias[0];
    u[e] = fminf(fmaxf(acc, -100.0f), -1e-6f);
}
__global__ __launch_bounds__(256) void init_pass(
    const int* __restrict__ dest_mask, float* v, float* s, int N)
{
    int n = blockIdx.x * blockDim.x + threadIdx.x;
    if (n >= N) return;
    v[n] = dest_mask[n] ? 0.0f : NEGV;
    s[n] = 0.0f;
}
__global__ __launch_bounds__(256) void edge_pass(
    const float* __restrict__ u, const int* __restrict__ src,
    const int* __restrict__ dst, const float* __restrict__ v, float* s, int E)
{
    int e = blockIdx.x * blockDim.x + threadIdx.x;
    if (e >= E) return;
    atomicAdd(&s[src[e]], expf(u[e] + v[dst[e]]));
}
__global__ __launch_bounds__(256) void node_pass(
    const int* __restrict__ dest_mask, float* v, float* s, int N)
{
    int n = blockIdx.x * blockDim.x + threadIdx.x;
    if (n >= N) return;
    float sv = s[n];
    v[n] = dest_mask[n] ? 0.0f : (sv > 0.0f ? logf(sv) : NEGV);
    s[n] = 0.0f;
}

// ---------------- host ----------------
extern "C" void kernel_launch(void* const* d_in, const int* in_sizes, int n_in,
                              void* d_out, int out_size, void* d_ws, size_t ws_size,
                              hipStream_t stream)
{
    const float* feats     = (const float*)d_in[0];
    const int*   dest_mask = (const int*)d_in[1];
    const int*   edge_index= (const int*)d_in[2];
    const float* weight    = (const float*)d_in[5];
    const float* bias      = (const float*)d_in[6];

    const int F = in_sizes[5];
    const int E = in_sizes[2] / 2;
    const int N = in_sizes[1];

    const int* src = edge_index;
    const int* dst = edge_index + E;

    float* out   = (float*)d_out;
    float* value = out;
    float* util  = out + N;
    float* prob  = out + (size_t)N + (size_t)E;

    const int eb = (E + 255) / 256;
    const int nb = (N + 255) / 256;

    const int W = (N + NBUCK - 1) / NBUCK;   // nodes per bucket

    // ws layout: cursors(NBUCK*CPAD) | edg(int2 NBUCK*REG) | row_ptr(N) | row_end(N) |
    //            ewa(N) | ewb(N) | flags(N_ITERS+1)
    const size_t need_words = (size_t)NBUCK * CPAD + 2 * (size_t)NBUCK * REG
                            + 4 * (size_t)N + (N_ITERS + 1);
    const size_t need_bytes = need_words * 4;
    const bool pack_ok = (N < (1 << 20)) && (W <= 128)
                      && ((size_t)NBUCK * REG >= (size_t)E)
                      && ((N & 1) == 0);   // keep flags int2-aligned

    if (d_ws != nullptr && ws_size >= need_bytes && pack_ok) {
        int*   cursors = (int*)d_ws;
        int2*  edg     = (int2*)(cursors + (size_t)NBUCK * CPAD);
        int*   row_ptr = (int*)(edg + (size_t)NBUCK * REG);
        int*   row_end = row_ptr + N;
        float* ewa     = (float*)(row_end + N);
        float* ewb     = ewa + N;
        int*   flags   = (int*)(ewb + N);

        // K1: util (+ cursor/flag init in block 0)
        if (F == 64) {
            util_kernel64gs<<<2048, 256, 0, stream>>>(
                feats, weight, bias, util, cursors, flags, E);
        } else {
            util_kernel<<<eb, 256, 0, stream>>>(
                feats, weight, bias, util, cursors, flags, E, F);
        }

        const int chunk = (E + B1 - 1) / B1;
        scatter_fused<<<B1, 256, 0, stream>>>(src, dst, util, cursors, edg, E, W, chunk);
        // fine_sort also computes ew1 (fused iteration 1) into ewa
        fine_sort<<<NBUCK, 256, 0, stream>>>(
            cursors, edg, row_ptr, row_end, dest_mask, ewa, N, W);

        const int gb = ((N * 8) + 255) / 256;   // 8 lanes per node
        float* cur = ewa;                        // holds ew1
        float* nxt = ewb;
        for (int it = 2; it <= N_ITERS - 1; ++it) {   // iterations 2..31
            iter_exp_conv<<<gb, 256, 0, stream>>>(
                row_ptr, row_end, edg, dest_mask, cur, nxt,
                flags + (it - 2), flags + it, N);
            float* t = cur; cur = nxt; nxt = t;
        }
        final_exp_conv<<<gb, 256, 0, stream>>>(
            row_ptr, row_end, edg, dest_mask, cur, value, flags + (N_ITERS - 1), N);

        prob_kernel<<<eb, 256, 0, stream>>>(util, src, dst, value, prob, E);
    } else {
        // fallback: atomic multi-launch path; s carved from prob region
        util_plain<<<eb, 256, 0, stream>>>(feats, weight, bias, util, E, F);
        float* s = prob;
        init_pass<<<nb, 256, 0, stream>>>(dest_mask, value, s, N);
        for (int it = 0; it < N_ITERS; ++it) {
            edge_pass<<<eb, 256, 0, stream>>>(util, src, dst, value, s, E);
            node_pass<<<nb, 256, 0, stream>>>(dest_mask, value, s, N);
        }
        prob_kernel<<<eb, 256, 0, stream>>>(util, src, dst, value, prob, E);
    }
}